// Round 7
// baseline (230.661 us; speedup 1.0000x reference)
//
#include <hip/hip_runtime.h>
#include <math.h>

// SoftSkeletonize: out = relu(img - dilate3(erode3(img))), (2,1,192,256,256) f32.
// erode = min-pool 3x3x3 (pad +inf), dilate = max-pool 3x3x3 (pad -inf).
//
// History:
// v2 (74.6us): raw+ebuf planes in LDS, z-pipes in regs, 2 barriers/plane.
// v3/v4 FAILED: launch_bounds 2nd arg >3 collapses VGPR -> scratch spill.
// v5 FAILED: 4 blocks/CU via CD=12 -> no gain. Not wave-starved.
// v6 NEUTRAL: conflicts 1.87e7->4.87e6 via shuffles -> no gain. Not conflict-bound.
// v7 NEUTRAL (76.5us): 1 barrier/plane + post-barrier prefetch -> no gain.
//   Diagnosis: per-block-iter ~2900cyc with NO pipe >50%: LDS ~1450cyc (50%),
//   VALU ~45%, VMEM ~25%. The global->LDS->reg (raw) and e->LDS->reg (ebuf)
//   round trips serialize all phases through the LDS pipe.
// v8 round 6: container failed twice (infra); kernel audited memory-safe,
//   resubmitted unchanged.
//
// v8: DELETE the raw LDS stage. B reads raw directly from global with
// predicated loads (+inf OOB fill == the old inf-padded LDS semantics).
// Vertical 3x reuse is served by L1 (3 blocks x 11.5KB ~= 32KB L1) / L2
// (~1MB per XCD << 4MB) -> HBM unique-line fetch unchanged. LDS per wave-iter
// drops ~364 -> ~155 cyc. ebuf TRIPLE-buffered (3 x 10.3KB = 31KB): B's
// e-write is provably race-free PRE-barrier (writer k and reader of the same
// buffer are >=1 barrier apart for all pairs) -> one barrier/plane with a
// clean [global-load + VALU] | barrier | [LDS D-phase + store] split.
// E's raw centers: global loads of plane zz in the SAME iter B reads that
// plane (cache-hot; v6's +18MB fetch came from multi-plane lag) -> rw pipe
// deepened to 4 stages.

#define D_ 192
#define H_ 256
#define W_ 256
#define NB 2
#define TH 32
#define TW 64
#define CD 16
#define NCHUNK (D_ / CD)      // 12

#define EB_H  (TH + 2)        // 34 rows  <-> gh = h0-1 .. h0+32
#define EB_W  (TW + 8)        // 72 cols  <-> gw = w0-4 .. w0+67
#define EB_S  76              // 304 B row stride (16B-aligned: 19*16)

#define NBTASK (EB_H * (EB_W / 8))     // 306 8-wide tasks

__device__ __forceinline__ float min3f(float a, float b, float c) {
    return fminf(fminf(a, b), c);
}
__device__ __forceinline__ float max3f(float a, float b, float c) {
    return fmaxf(fmaxf(a, b), c);
}

__global__ __launch_bounds__(256, 3)
void soft_skel_v8(const float* __restrict__ img, float* __restrict__ out) {
    __shared__ __align__(16) float ebuf[3][EB_H][EB_S];   // 31.0 KB

    const int tid  = threadIdx.x;
    const int lane = tid & 63;
    const int w0 = blockIdx.x * TW;
    const int h0 = blockIdx.y * TH;
    const int n  = blockIdx.z / NCHUNK;
    const int ch = blockIdx.z - n * NCHUNK;
    const int z0 = ch * CD;

    const float* vol  = img + (size_t)n * (D_ * H_ * W_);
    float*       ovol = out + (size_t)n * (D_ * H_ * W_);

    const float PINF = INFINITY;

    // ---- B-stage task geometry (8-wide strips over 34x72 e-region)
    const int  r0 = tid / 9;
    const int  c0 = (tid - r0 * 9) * 8;
    const bool has1 = tid < (NBTASK - 256);    // 50 lanes of wave 0
    const int  t1 = tid + 256;
    const int  r1 = t1 / 9;
    const int  c1 = (t1 - r1 * 9) * 8;

    // ---- D/E geometry: thread owns tile row ty, cols xx..xx+7
    const int ty = tid >> 3;
    const int cx = tid & 7;
    const int xx = cx * 8;

    // ---- invariant global addressing + masks per task
    int  ro0[3], ro1[3];
    bool rk0[3], rk1[3];
    const int g0 = w0 - 4 + c0;
    const int g1 = w0 - 4 + c1;
    #pragma unroll
    for (int i = 0; i < 3; ++i) {
        int gh0 = h0 - 2 + r0 + i;             // image rows for vertical min
        rk0[i] = (unsigned)gh0 < (unsigned)H_;
        ro0[i] = gh0 * W_ + g0;
        int gh1 = h0 - 2 + r1 + i;
        rk1[i] = (unsigned)gh1 < (unsigned)H_;
        ro1[i] = gh1 * W_ + g1;
    }
    const bool ck0a = (unsigned)g0       <= (unsigned)(W_ - 4);
    const bool ck0b = (unsigned)(g0 + 4) <= (unsigned)(W_ - 4);
    const bool ck1a = (unsigned)g1       <= (unsigned)(W_ - 4);
    const bool ck1b = (unsigned)(g1 + 4) <= (unsigned)(W_ - 4);
    const bool cl0 = (unsigned)(g0 - 1) < (unsigned)W_;
    const bool cr0 = (unsigned)(g0 + 8) < (unsigned)W_;
    const bool cl1 = (unsigned)(g1 - 1) < (unsigned)W_;
    const bool cr1 = (unsigned)(g1 + 8) < (unsigned)W_;
    const int coff = (h0 + ty) * W_ + (w0 + xx);   // always in-image

    // ---- register z-pipelines
    float pm0[8], sp0[8], pm1[8], sp1[8];      // erode z-min state per B task
    float t2A[8], t2B[8], t2C[8];              // t2(e) planes zz-4, zz-3, zz-2
    float rw0[8], rw1[8], rw2[8], rw3[8];      // raw centers zz-3 .. zz
    #pragma unroll
    for (int j = 0; j < 8; ++j) {
        pm0[j] = sp0[j] = pm1[j] = sp1[j] = PINF;
        t2A[j] = t2B[j] = 0.f;
        rw0[j] = rw1[j] = rw2[j] = 0.f;
    }

    auto ld4 = [&](const float* p, bool ok) -> float4 {
        return ok ? *(const float4*)p : make_float4(PINF, PINF, PINF, PINF);
    };
    auto ld1 = [&](const float* p, bool ok) -> float {
        return ok ? *p : PINF;
    };

    // B task: direct-global 3x3 vertical+horizontal min -> s; e(zz-1) =
    // min(pm, s) (masked -inf outside image for the dilate); update z-pipe;
    // write e into ebw. shfl_edges: neighbor lane holds adjacent column's
    // vertical min (consecutive tid == consecutive task).
    auto btask = [&](const float* pz, bool zokB, bool zeok, bool shfl_edges,
                     int r, int cb, const int* ro, const bool* rk,
                     bool cka, bool ckb, bool cl, bool cr,
                     float* pm, float* sp, float (*ebw)[EB_S]) {
        float4 q00 = ld4(pz + ro[0],     zokB && rk[0] && cka);
        float4 q01 = ld4(pz + ro[0] + 4, zokB && rk[0] && ckb);
        float4 q10 = ld4(pz + ro[1],     zokB && rk[1] && cka);
        float4 q11 = ld4(pz + ro[1] + 4, zokB && rk[1] && ckb);
        float4 q20 = ld4(pz + ro[2],     zokB && rk[2] && cka);
        float4 q21 = ld4(pz + ro[2] + 4, zokB && rk[2] && ckb);
        float v[8];
        v[0] = min3f(q00.x, q10.x, q20.x);
        v[1] = min3f(q00.y, q10.y, q20.y);
        v[2] = min3f(q00.z, q10.z, q20.z);
        v[3] = min3f(q00.w, q10.w, q20.w);
        v[4] = min3f(q01.x, q11.x, q21.x);
        v[5] = min3f(q01.y, q11.y, q21.y);
        v[6] = min3f(q01.z, q11.z, q21.z);
        v[7] = min3f(q01.w, q11.w, q21.w);

        float vL, vR;
        if (shfl_edges) {
            vL = __shfl_up(v[7], 1);
            vR = __shfl_down(v[0], 1);
            if (lane == 0) {
                vL = min3f(ld1(pz + ro[0] - 1, zokB && rk[0] && cl),
                           ld1(pz + ro[1] - 1, zokB && rk[1] && cl),
                           ld1(pz + ro[2] - 1, zokB && rk[2] && cl));
            }
            if (lane == 63) {
                vR = min3f(ld1(pz + ro[0] + 8, zokB && rk[0] && cr),
                           ld1(pz + ro[1] + 8, zokB && rk[1] && cr),
                           ld1(pz + ro[2] + 8, zokB && rk[2] && cr));
            }
        } else {
            vL = min3f(ld1(pz + ro[0] - 1, zokB && rk[0] && cl),
                       ld1(pz + ro[1] - 1, zokB && rk[1] && cl),
                       ld1(pz + ro[2] - 1, zokB && rk[2] && cl));
            vR = min3f(ld1(pz + ro[0] + 8, zokB && rk[0] && cr),
                       ld1(pz + ro[1] + 8, zokB && rk[1] && cr),
                       ld1(pz + ro[2] + 8, zokB && rk[2] && cr));
        }

        float s[8];
        s[0] = min3f(vL, v[0], v[1]);
        #pragma unroll
        for (int j = 1; j < 7; ++j) s[j] = min3f(v[j - 1], v[j], v[j + 1]);
        s[7] = min3f(v[6], v[7], vR);

        const bool rok = zeok && ((unsigned)(h0 - 1 + r) < (unsigned)H_);
        float e[8];
        #pragma unroll
        for (int j = 0; j < 8; ++j) {
            float ev = fminf(pm[j], s[j]);
            bool ok = rok && ((unsigned)(w0 - 4 + cb + j) < (unsigned)W_);
            e[j] = ok ? ev : -PINF;
            pm[j] = fminf(sp[j], s[j]);
            sp[j] = s[j];
        }
        *(float4*)&ebw[r][cb]     = make_float4(e[0], e[1], e[2], e[3]);
        *(float4*)&ebw[r][cb + 4] = make_float4(e[4], e[5], e[6], e[7]);
    };

    int cur = 0;
    const int zzend = z0 + CD + 2;

    for (int zz = z0 - 2; zz <= zzend; ++zz) {
        const int prv = (cur == 0) ? 2 : cur - 1;
        float (*ebw)[EB_S]       = ebuf[cur];
        const float (*ebp)[EB_S] = ebuf[prv];
        const float* pz = vol + (long long)zz * (H_ * W_);
        // zokB also skips the last, never-consumed e-plane's loads
        const bool zokB = (zz >= 0) && (zz < D_) && (zz <= z0 + CD + 1);
        const bool zeok = (zz - 1 >= 0) && (zz - 1 < D_);

        // ---- centers of plane zz (same lines B reads this iter -> cache-hot)
        float4 c0v = ld4(pz + coff,     zokB);
        float4 c1v = ld4(pz + coff + 4, zokB);

        // ---- B (PRE-barrier; triple-buffered ebuf makes the write race-free):
        btask(pz, zokB, zeok, true, r0, c0, ro0, rk0, ck0a, ck0b, cl0, cr0,
              pm0, sp0, ebw);
        if (has1)
            btask(pz, zokB, zeok, true, r1, c1, ro1, rk1, ck1a, ck1b, cl1, cr1,
                  pm1, sp1, ebw);

        rw3[0] = c0v.x; rw3[1] = c0v.y; rw3[2] = c0v.z; rw3[3] = c0v.w;
        rw3[4] = c1v.x; rw3[5] = c1v.y; rw3[6] = c1v.z; rw3[7] = c1v.w;

        __syncthreads();   // the ONLY barrier per plane

        // ---- D: 2D 3x3 max of e(zz-2) from ebuf[prv] -> t2C
        {
            const float* p0 = &ebp[ty][0];
            const float* p1 = &ebp[ty + 1][0];
            const float* p2 = &ebp[ty + 2][0];
            float4 q00 = *(const float4*)(p0 + xx + 4);
            float4 q01 = *(const float4*)(p0 + xx + 8);
            float4 q10 = *(const float4*)(p1 + xx + 4);
            float4 q11 = *(const float4*)(p1 + xx + 8);
            float4 q20 = *(const float4*)(p2 + xx + 4);
            float4 q21 = *(const float4*)(p2 + xx + 8);
            float t[8];
            t[0] = max3f(q00.x, q10.x, q20.x);
            t[1] = max3f(q00.y, q10.y, q20.y);
            t[2] = max3f(q00.z, q10.z, q20.z);
            t[3] = max3f(q00.w, q10.w, q20.w);
            t[4] = max3f(q01.x, q11.x, q21.x);
            t[5] = max3f(q01.y, q11.y, q21.y);
            t[6] = max3f(q01.z, q11.z, q21.z);
            t[7] = max3f(q01.w, q11.w, q21.w);

            float tL = __shfl_up(t[7], 1);     // col xx+3
            float tR = __shfl_down(t[0], 1);   // col xx+12
            if (cx == 0) {
                tL = max3f(p0[xx + 3], p1[xx + 3], p2[xx + 3]);
            }
            if (cx == 7) {
                tR = max3f(p0[xx + 12], p1[xx + 12], p2[xx + 12]);
            }
            t2C[0] = max3f(tL, t[0], t[1]);
            #pragma unroll
            for (int j = 1; j < 7; ++j) t2C[j] = max3f(t[j - 1], t[j], t[j + 1]);
            t2C[7] = max3f(t[6], t[7], tR);
        }

        // ---- E: output plane z = zz-3: relu(raw - max over t2 planes)
        if (zz >= z0 + 3) {
            const int z = zz - 3;
            float* op = ovol + ((size_t)z * H_ + (h0 + ty)) * W_ + (w0 + xx);
            float o[8];
            #pragma unroll
            for (int j = 0; j < 8; ++j) {
                float opened = max3f(t2A[j], t2B[j], t2C[j]);
                float v = rw0[j] - opened;
                o[j] = v > 0.f ? v : 0.f;
            }
            *(float4*)op       = make_float4(o[0], o[1], o[2], o[3]);
            *(float4*)(op + 4) = make_float4(o[4], o[5], o[6], o[7]);
        }

        // ---- shift register pipelines
        #pragma unroll
        for (int j = 0; j < 8; ++j) {
            t2A[j] = t2B[j]; t2B[j] = t2C[j];
            rw0[j] = rw1[j]; rw1[j] = rw2[j]; rw2[j] = rw3[j];
        }
        cur = (cur == 2) ? 0 : cur + 1;
    }
}

extern "C" void kernel_launch(void* const* d_in, const int* in_sizes, int n_in,
                              void* d_out, int out_size, void* d_ws, size_t ws_size,
                              hipStream_t stream) {
    const float* img = (const float*)d_in[0];
    float* out = (float*)d_out;

    dim3 grid(W_ / TW, H_ / TH, NB * NCHUNK);   // (4, 8, 24) = 768 blocks
    dim3 block(256);
    soft_skel_v8<<<grid, block, 0, stream>>>(img, out);
}

// Round 8
// 193.322 us; speedup vs baseline: 1.1931x; 1.1931x over previous
//
#include <hip/hip_runtime.h>
#include <math.h>

// SoftSkeletonize: out = relu(img - dilate3(erode3(img))), (2,1,192,256,256) f32.
// erode = min-pool 3x3x3 (pad +inf), dilate = max-pool 3x3x3 (pad -inf).
//
// History (per-dispatch dur / normalized cyc per block-iter):
// v2 74.6us / 2987: raw+ebuf in LDS, z-pipes in regs, 2 barriers/plane. BEST.
// v3/v4 FAILED: launch_bounds 2nd arg >3 collapses VGPR -> scratch spill.
// v5 83.7 / 3140: 4 blocks/CU (CD=12) -> per-block throughput WORSE. Not wave-starved.
// v6 77.5 / 3100: shuffle edge-fix (conflicts 1.75e7->4.87e6, real ~3-4us win)
//    BUT global-A2 added +18MB fetch (~+6us) -> net loss. CONFOUNDED EXPERIMENT.
// v7 76.5 / 3060: 1 barrier/plane + dbuf -> neutral. Barrier count not the limiter.
// v8 112.6 / 4290: no-LDS (direct-global B) -> VMEM issues x2.5 at ~200cyc L1/L2
//    latency, 12 waves can't hide it. LDS round-trip was NOT the limiter.
//
// v9 = v2 + shuffle edge-fix ONLY (v6 decontaminated: A2 stays an LDS read).
// Rationale: v2's LDS pipe incl. conflicts ~74% busy = highest-utilization
// resource; the conflict half (~3400 cyc/CU-iter) comes from full-wave scalar
// edge reads (all float4-aligned addrs + stride 76 == 12 mod 32 -> 8 banks,
// 8-way). Neighbor lane already holds the adjacent column's vertical min/max
// -> __shfl_up/__shfl_down (conflict-free) replace them; 1-2 boundary lanes
// per wave use predicated scalar fallbacks.

#define D_ 192
#define H_ 256
#define W_ 256
#define NB 2
#define TH 32
#define TW 64
#define CD 16
#define NCHUNK (D_ / CD)      // 12

#define RAW_H (TH + 4)        // 36 rows  <-> gh = h0-2 .. h0+33
#define RAW_W (TW + 8)        // 72 cols  <-> gw = w0-4 .. w0+67
#define RAW_S 76              // padded stride
#define EB_H  (TH + 2)        // 34 rows  <-> gh = h0-1 .. h0+32
#define EB_W  (TW + 8)        // 72 cols
#define EB_S  76

#define NRAWF4 (RAW_H * (RAW_W / 4))   // 648 float4 cells
#define NBTASK (EB_H * (EB_W / 8))     // 306 8-wide tasks

__device__ __forceinline__ float min3f(float a, float b, float c) {
    return fminf(fminf(a, b), c);
}
__device__ __forceinline__ float max3f(float a, float b, float c) {
    return fmaxf(fmaxf(a, b), c);
}

__global__ __launch_bounds__(256, 3)
void soft_skel_v9(const float* __restrict__ img, float* __restrict__ out) {
    __shared__ __align__(16) float raw[RAW_H][RAW_S];
    __shared__ __align__(16) float ebuf[EB_H][EB_S];

    const int tid  = threadIdx.x;
    const int lane = tid & 63;
    const int w0 = blockIdx.x * TW;
    const int h0 = blockIdx.y * TH;
    const int n  = blockIdx.z / NCHUNK;
    const int ch = blockIdx.z - n * NCHUNK;
    const int z0 = ch * CD;

    const float* vol  = img + (size_t)n * (D_ * H_ * W_);
    float*       ovol = out + (size_t)n * (D_ * H_ * W_);

    const float PINF = INFINITY;

    // ---- A-stage per-thread geometry: 3 float4 slots cover the 36x72 region
    bool a_slot[3], a_img[3];
    int  a_lds[3], a_off[3];
    #pragma unroll
    for (int k = 0; k < 3; ++k) {
        int idx = tid + 256 * k;
        bool slot = idx < NRAWF4;
        int row = idx / (RAW_W / 4);           // /18
        int cg  = idx - row * (RAW_W / 4);
        int gh = h0 - 2 + row;
        int gw = w0 - 4 + 4 * cg;
        a_slot[k] = slot;
        a_img[k]  = slot && (gh >= 0) && (gh < H_) && (gw >= 0) && (gw <= W_ - 4);
        a_off[k]  = gh * W_ + gw;
        a_lds[k]  = slot ? (row * RAW_S + 4 * cg) : 0;
    }

    // ---- B-stage task geometry (8-wide strips over 34x72 region)
    const int  r0 = tid / 9;
    const int  c0 = (tid - r0 * 9) * 8;
    const bool has1 = tid < (NBTASK - 256);    // 50 threads take a 2nd task
    const int  t1 = tid + 256;
    const int  r1 = t1 / 9;
    const int  c1 = (t1 - r1 * 9) * 8;

    // ---- D/E geometry: thread owns tile row ty, cols xx..xx+7
    const int ty = tid >> 3;
    const int cx = tid & 7;
    const int xx = cx * 8;

    // ---- register z-pipelines
    float pm0[8], sp0[8], pm1[8], sp1[8];      // erode z-min state per B task
    float t2A[8], t2B[8], t2C[8];              // 2D-max planes z-1, z, z+1
    float rwA[8], rwB[8], rwC[8];              // raw centers z, z+1, z+2
    #pragma unroll
    for (int j = 0; j < 8; ++j) {
        pm0[j] = sp0[j] = pm1[j] = sp1[j] = PINF;
        t2A[j] = t2B[j] = 0.f;
        rwA[j] = rwB[j] = 0.f;
    }

    auto prefetch = [&](int zz, float4 L[3]) {
        const bool zok = (zz >= 0) && (zz < D_);
        const float* plane = vol + (size_t)zz * (H_ * W_);
        #pragma unroll
        for (int k = 0; k < 3; ++k) {
            float4 v = make_float4(PINF, PINF, PINF, PINF);
            if (zok && a_img[k]) v = *(const float4*)(plane + a_off[k]);
            L[k] = v;
        }
    };

    // B task: 2D 3x3 min of raw -> s; e(zz-1) = min(pm, s) (masked); update pipe.
    // Edge columns via intra-wave shuffle (consecutive tid == consecutive task);
    // wave-boundary lanes use predicated scalar fallbacks (conflict-free).
    auto btask = [&](int r, int cb, float pm[8], float sp[8], bool zeok) {
        float4 q00 = *(const float4*)(&raw[r][cb]);
        float4 q01 = *(const float4*)(&raw[r][cb + 4]);
        float4 q10 = *(const float4*)(&raw[r + 1][cb]);
        float4 q11 = *(const float4*)(&raw[r + 1][cb + 4]);
        float4 q20 = *(const float4*)(&raw[r + 2][cb]);
        float4 q21 = *(const float4*)(&raw[r + 2][cb + 4]);
        float v[8];
        v[0] = min3f(q00.x, q10.x, q20.x);
        v[1] = min3f(q00.y, q10.y, q20.y);
        v[2] = min3f(q00.z, q10.z, q20.z);
        v[3] = min3f(q00.w, q10.w, q20.w);
        v[4] = min3f(q01.x, q11.x, q21.x);
        v[5] = min3f(q01.y, q11.y, q21.y);
        v[6] = min3f(q01.z, q11.z, q21.z);
        v[7] = min3f(q01.w, q11.w, q21.w);

        float vL = __shfl_up(v[7], 1);     // neighbor task's col cb-1
        float vR = __shfl_down(v[0], 1);   // neighbor task's col cb+8
        if (lane == 0) {
            int cl = cb - 1; if (cl < 0) cl = 0;
            vL = min3f(raw[r][cl], raw[r + 1][cl], raw[r + 2][cl]);
        }
        if (lane == 63) {
            int cr = cb + 8; if (cr > RAW_W - 1) cr = RAW_W - 1;
            vR = min3f(raw[r][cr], raw[r + 1][cr], raw[r + 2][cr]);
        }

        float s[8];
        s[0] = min3f(vL, v[0], v[1]);
        #pragma unroll
        for (int j = 1; j < 7; ++j) s[j] = min3f(v[j - 1], v[j], v[j + 1]);
        s[7] = min3f(v[6], v[7], vR);

        const bool rok = zeok && ((unsigned)(h0 - 1 + r) < (unsigned)H_);
        float e[8];
        #pragma unroll
        for (int j = 0; j < 8; ++j) {
            float ev = fminf(pm[j], s[j]);
            bool ok = rok && ((unsigned)(w0 - 4 + cb + j) < (unsigned)W_);
            e[j] = ok ? ev : -PINF;
            pm[j] = fminf(sp[j], s[j]);
            sp[j] = s[j];
        }
        *(float4*)&ebuf[r][cb]     = make_float4(e[0], e[1], e[2], e[3]);
        *(float4*)&ebuf[r][cb + 4] = make_float4(e[4], e[5], e[6], e[7]);
    };

    float4 L[3];
    prefetch(z0 - 2, L);
    const int zzend = z0 + CD + 1;

    for (int zz = z0 - 2; zz <= zzend; ++zz) {
        // ---- A: commit prefetched raw plane zz to LDS, start loading zz+1
        #pragma unroll
        for (int k = 0; k < 3; ++k)
            if (a_slot[k]) *(float4*)(&raw[0][0] + a_lds[k]) = L[k];
        if (zz < zzend) prefetch(zz + 1, L);
        __syncthreads();

        // ---- A2: capture raw centers of plane zz from LDS (b128, conflict-light)
        {
            float4 v0 = *(const float4*)&raw[ty + 2][xx + 4];
            float4 v1 = *(const float4*)&raw[ty + 2][xx + 8];
            rwC[0] = v0.x; rwC[1] = v0.y; rwC[2] = v0.z; rwC[3] = v0.w;
            rwC[4] = v1.x; rwC[5] = v1.y; rwC[6] = v1.z; rwC[7] = v1.w;
        }

        // ---- B: s2d(zz) + full erode e(zz-1) -> ebuf
        const int  ze   = zz - 1;
        const bool zeok = (ze >= 0) && (ze < D_);
        btask(r0, c0, pm0, sp0, zeok);
        if (has1) btask(r1, c1, pm1, sp1, zeok);
        __syncthreads();

        // ---- D: 2D 3x3 max of e(zz-1) -> t2C (registers)
        {
            const float* p0 = &ebuf[ty][0];
            const float* p1 = &ebuf[ty + 1][0];
            const float* p2 = &ebuf[ty + 2][0];
            float4 q00 = *(const float4*)(p0 + xx + 4);
            float4 q01 = *(const float4*)(p0 + xx + 8);
            float4 q10 = *(const float4*)(p1 + xx + 4);
            float4 q11 = *(const float4*)(p1 + xx + 8);
            float4 q20 = *(const float4*)(p2 + xx + 4);
            float4 q21 = *(const float4*)(p2 + xx + 8);
            float t[8];
            t[0] = max3f(q00.x, q10.x, q20.x);
            t[1] = max3f(q00.y, q10.y, q20.y);
            t[2] = max3f(q00.z, q10.z, q20.z);
            t[3] = max3f(q00.w, q10.w, q20.w);
            t[4] = max3f(q01.x, q11.x, q21.x);
            t[5] = max3f(q01.y, q11.y, q21.y);
            t[6] = max3f(q01.z, q11.z, q21.z);
            t[7] = max3f(q01.w, q11.w, q21.w);

            float tL = __shfl_up(t[7], 1);     // col xx+3
            float tR = __shfl_down(t[0], 1);   // col xx+12
            if (cx == 0) {
                tL = max3f(p0[xx + 3], p1[xx + 3], p2[xx + 3]);
            }
            if (cx == 7) {
                tR = max3f(p0[xx + 12], p1[xx + 12], p2[xx + 12]);
            }
            t2C[0] = max3f(tL, t[0], t[1]);
            #pragma unroll
            for (int j = 1; j < 7; ++j) t2C[j] = max3f(t[j - 1], t[j], t[j + 1]);
            t2C[7] = max3f(t[6], t[7], tR);
        }

        // ---- E: output plane z = zz-2: relu(raw - max over t2 planes)
        if (zz >= z0 + 2) {
            const int z = zz - 2;
            float* op = ovol + ((size_t)z * H_ + (h0 + ty)) * W_ + (w0 + xx);
            float o[8];
            #pragma unroll
            for (int j = 0; j < 8; ++j) {
                float opened = max3f(t2A[j], t2B[j], t2C[j]);
                float v = rwA[j] - opened;
                o[j] = v > 0.f ? v : 0.f;
            }
            *(float4*)op       = make_float4(o[0], o[1], o[2], o[3]);
            *(float4*)(op + 4) = make_float4(o[4], o[5], o[6], o[7]);
        }

        // ---- shift register pipelines
        #pragma unroll
        for (int j = 0; j < 8; ++j) {
            t2A[j] = t2B[j]; t2B[j] = t2C[j];
            rwA[j] = rwB[j]; rwB[j] = rwC[j];
        }
    }
}

extern "C" void kernel_launch(void* const* d_in, const int* in_sizes, int n_in,
                              void* d_out, int out_size, void* d_ws, size_t ws_size,
                              hipStream_t stream) {
    const float* img = (const float*)d_in[0];
    float* out = (float*)d_out;

    dim3 grid(W_ / TW, H_ / TH, NB * NCHUNK);   // (4, 8, 24) = 768 blocks
    dim3 block(256);
    soft_skel_v9<<<grid, block, 0, stream>>>(img, out);
}